// Round 3
// baseline (243.346 us; speedup 1.0000x reference)
//
#include <hip/hip_runtime.h>
#include <math.h>

#define ALPHA 0.7f
#define EPSF  1e-7f

// focal element: pt = pos ? p : 1-p; lg = -log(pt) (inf -> 1e-7);
// f = (1-pt)^2 * lg; pos gets * ALPHA
// __logf -> v_log_f32; v_log_f32(0) = -inf so the inf->EPS path is preserved.
__device__ __forceinline__ float focal_elem(float p, int y) {
    const bool pos = (y == 1);
    const float pt = pos ? p : 1.0f - p;
    float lg = -__logf(pt);
    if (isinf(lg)) lg = EPSF;
    const float om = 1.0f - pt;
    float f = om * om * lg;
    return pos ? f * ALPHA : f;
}

__device__ __forceinline__ float focal4(const float4 pv, const int4 yv) {
    float a = focal_elem(pv.x, yv.x);
    a += focal_elem(pv.y, yv.y);
    a += focal_elem(pv.z, yv.z);
    a += focal_elem(pv.w, yv.w);
    return a;
}

template <int BLOCK>
__device__ __forceinline__ float block_reduce(float acc) {
    #pragma unroll
    for (int off = 32; off > 0; off >>= 1)
        acc += __shfl_down(acc, off, 64);
    __shared__ float smem[BLOCK / 64];
    const int lane = threadIdx.x & 63;
    const int wave = threadIdx.x >> 6;
    if (lane == 0) smem[wave] = acc;
    __syncthreads();
    float s = 0.0f;
    if (threadIdx.x == 0) {
        #pragma unroll
        for (int w = 0; w < BLOCK / 64; ++w) s += smem[w];
    }
    return s;
}

// Each block owns a contiguous VPB float4s (256 KB per stream). Fully unrolled,
// bounds-check-free body -> compiler can batch-issue independent dwordx4 loads
// with staggered vmcnt waits (copy-benchmark structure).
template <int BLOCK, int VPB>   // VPB = float4s per block
__global__ void __launch_bounds__(BLOCK, 4)
focal_partial(const float* __restrict__ p, const int* __restrict__ y,
              float* __restrict__ partial, long long n) {
    constexpr int ITERS = VPB / BLOCK;  // 16
    const long long n4 = n >> 2;
    const float4* __restrict__ p4 = (const float4*)p;
    const int4*   __restrict__ y4 = (const int4*)y;
    const long long base = (long long)blockIdx.x * VPB;
    const int t = threadIdx.x;

    float acc = 0.0f;
    if (base + VPB <= n4) {
        // fast path: fully static, no bounds checks
        #pragma unroll
        for (int u = 0; u < ITERS; ++u) {
            const long long i = base + (long long)u * BLOCK + t;
            acc += focal4(p4[i], y4[i]);
        }
    } else {
        // tail block (not hit for the bench shape: n4 % VPB == 0)
        for (long long i = base + t; i < n4; i += BLOCK)
            acc += focal4(p4[i], y4[i]);
    }
    // scalar remainder (n % 4), done once by the last block
    if (blockIdx.x == gridDim.x - 1 && t == 0) {
        for (long long j = n4 << 2; j < n; ++j)
            acc += focal_elem(p[j], y[j]);
    }

    const float s = block_reduce<BLOCK>(acc);
    if (t == 0) partial[blockIdx.x] = s;
}

template <int BLOCK>
__global__ void __launch_bounds__(BLOCK)
focal_final(const float* __restrict__ partial, int nparts,
            float* __restrict__ out, long long n) {
    float acc = 0.0f;
    for (int i = threadIdx.x; i < nparts; i += BLOCK) acc += partial[i];
    const float s = block_reduce<BLOCK>(acc);
    if (threadIdx.x == 0) out[0] = s / (float)n;
}

extern "C" void kernel_launch(void* const* d_in, const int* in_sizes, int n_in,
                              void* d_out, int out_size, void* d_ws, size_t ws_size,
                              hipStream_t stream) {
    const float* p = (const float*)d_in[0];
    const int*   y = (const int*)d_in[1];
    float* out = (float*)d_out;
    float* partial = (float*)d_ws;

    const long long n = (long long)in_sizes[0];
    constexpr int BLOCK = 256;
    constexpr int VPB = 4096;  // float4s per block: 256 KB of p + 256 KB of y
    const long long n4 = n >> 2;
    int nblocks = (int)((n4 + VPB - 1) / VPB);  // 1728 for n=28,311,552 (exact)
    if (nblocks < 1) nblocks = 1;

    focal_partial<BLOCK, VPB><<<nblocks, BLOCK, 0, stream>>>(p, y, partial, n);
    focal_final<BLOCK><<<1, BLOCK, 0, stream>>>(partial, nblocks, out, n);
}

// Round 4
// 240.155 us; speedup vs baseline: 1.0133x; 1.0133x over previous
//
#include <hip/hip_runtime.h>
#include <math.h>

#define ALPHA 0.7f
#define EPSF  1e-7f

// focal element: pt = pos ? p : 1-p; lg = -log(pt) (inf -> 1e-7);
// f = (1-pt)^2 * lg; pos gets * ALPHA
// __logf -> v_log_f32; v_log_f32(0) = -inf so the inf->EPS path is preserved.
__device__ __forceinline__ float focal_elem(float p, int y) {
    const bool pos = (y == 1);
    const float pt = pos ? p : 1.0f - p;
    float lg = -__logf(pt);
    if (isinf(lg)) lg = EPSF;
    const float om = 1.0f - pt;
    float f = om * om * lg;
    return pos ? f * ALPHA : f;
}

__device__ __forceinline__ float focal4(const float4 pv, const int4 yv) {
    float a = focal_elem(pv.x, yv.x);
    a += focal_elem(pv.y, yv.y);
    a += focal_elem(pv.z, yv.z);
    a += focal_elem(pv.w, yv.w);
    return a;
}

template <int BLOCK>
__device__ __forceinline__ float block_reduce(float acc) {
    #pragma unroll
    for (int off = 32; off > 0; off >>= 1)
        acc += __shfl_down(acc, off, 64);
    __shared__ float smem[BLOCK / 64];
    const int lane = threadIdx.x & 63;
    const int wave = threadIdx.x >> 6;
    if (lane == 0) smem[wave] = acc;
    __syncthreads();
    float s = 0.0f;
    if (threadIdx.x == 0) {
        #pragma unroll
        for (int w = 0; w < BLOCK / 64; ++w) s += smem[w];
    }
    return s;
}

// Explicit software pipeline: D float4+int4 pairs per batch, double-buffered
// in registers. The rotation dependency FORCES >= D pairs (8 KB/wave at D=4)
// outstanding while computing the previous batch — the compiler cannot shrink
// the window (R1-R3 all compiled to a ~2-load window, VGPR 16-28).
template <int BLOCK, int D, int CHUNKS>
__global__ void __launch_bounds__(BLOCK, 4)
focal_partial(const float* __restrict__ p, const int* __restrict__ y,
              float* __restrict__ partial, long long n) {
    constexpr int VPB = BLOCK * D * CHUNKS;  // float4s per block
    const long long n4 = n >> 2;
    const float4* __restrict__ p4 = (const float4*)p;
    const int4*   __restrict__ y4 = (const int4*)y;
    const long long blk = (long long)blockIdx.x * VPB;
    const int t = threadIdx.x;

    float acc = 0.0f;
    if (blk + VPB <= n4) {
        const long long base = blk + t;
        float4 pv[D]; int4 yv[D];
        // prologue: batch 0 in flight
        #pragma unroll
        for (int d = 0; d < D; ++d) {
            pv[d] = p4[base + d * BLOCK];
            yv[d] = y4[base + d * BLOCK];
        }
        #pragma unroll 1   // keep rolled: preserve the pipeline structure
        for (int c = 1; c < CHUNKS; ++c) {
            float4 np[D]; int4 ny[D];
            const long long cb = base + (long long)c * (D * BLOCK);
            #pragma unroll
            for (int d = 0; d < D; ++d) {
                np[d] = p4[cb + d * BLOCK];
                ny[d] = y4[cb + d * BLOCK];
            }
            #pragma unroll
            for (int d = 0; d < D; ++d) acc += focal4(pv[d], yv[d]);
            #pragma unroll
            for (int d = 0; d < D; ++d) { pv[d] = np[d]; yv[d] = ny[d]; }
        }
        #pragma unroll
        for (int d = 0; d < D; ++d) acc += focal4(pv[d], yv[d]);
    } else {
        // tail block (not hit for the bench shape)
        for (long long i = blk + t; i < n4; i += BLOCK)
            acc += focal4(p4[i], y4[i]);
    }
    // scalar remainder (n % 4), done once by the last block
    if (blockIdx.x == gridDim.x - 1 && t == 0) {
        for (long long j = n4 << 2; j < n; ++j)
            acc += focal_elem(p[j], y[j]);
    }

    const float s = block_reduce<BLOCK>(acc);
    if (t == 0) partial[blockIdx.x] = s;
}

template <int BLOCK>
__global__ void __launch_bounds__(BLOCK)
focal_final(const float* __restrict__ partial, int nparts,
            float* __restrict__ out, long long n) {
    float acc = 0.0f;
    for (int i = threadIdx.x; i < nparts; i += BLOCK) acc += partial[i];
    const float s = block_reduce<BLOCK>(acc);
    if (threadIdx.x == 0) out[0] = s / (float)n;
}

extern "C" void kernel_launch(void* const* d_in, const int* in_sizes, int n_in,
                              void* d_out, int out_size, void* d_ws, size_t ws_size,
                              hipStream_t stream) {
    const float* p = (const float*)d_in[0];
    const int*   y = (const int*)d_in[1];
    float* out = (float*)d_out;
    float* partial = (float*)d_ws;

    const long long n = (long long)in_sizes[0];
    constexpr int BLOCK = 256;
    constexpr int D = 4;       // pairs in flight per wave: 4 x (16B+16B) x 64 lanes = 8 KB
    constexpr int CHUNKS = 4;  // VPB = 4096 float4s per block, same as R3
    constexpr int VPB = BLOCK * D * CHUNKS;
    const long long n4 = n >> 2;
    int nblocks = (int)((n4 + VPB - 1) / VPB);  // 1728 for n=28,311,552 (exact)
    if (nblocks < 1) nblocks = 1;

    focal_partial<BLOCK, D, CHUNKS><<<nblocks, BLOCK, 0, stream>>>(p, y, partial, n);
    focal_final<BLOCK><<<1, BLOCK, 0, stream>>>(partial, nblocks, out, n);
}

// Round 5
// 218.872 us; speedup vs baseline: 1.1118x; 1.0972x over previous
//
#include <hip/hip_runtime.h>
#include <math.h>

#define ALPHA 0.7f
#define EPSF  1e-7f

// clang ext_vector types so __builtin_nontemporal_load accepts them
typedef float f32x4 __attribute__((ext_vector_type(4)));
typedef int   i32x4 __attribute__((ext_vector_type(4)));

// focal element: pt = pos ? p : 1-p; lg = -log(pt) (inf -> 1e-7);
// f = (1-pt)^2 * lg; pos gets * ALPHA
// __logf -> v_log_f32; v_log_f32(0) = -inf so the inf->EPS path is preserved.
__device__ __forceinline__ float focal_elem(float p, int y) {
    const bool pos = (y == 1);
    const float pt = pos ? p : 1.0f - p;
    float lg = -__logf(pt);
    if (isinf(lg)) lg = EPSF;
    const float om = 1.0f - pt;
    float f = om * om * lg;
    return pos ? f * ALPHA : f;
}

__device__ __forceinline__ float focal4(const f32x4 pv, const i32x4 yv) {
    float a = focal_elem(pv.x, yv.x);
    a += focal_elem(pv.y, yv.y);
    a += focal_elem(pv.z, yv.z);
    a += focal_elem(pv.w, yv.w);
    return a;
}

template <int BLOCK>
__device__ __forceinline__ float block_reduce(float acc) {
    #pragma unroll
    for (int off = 32; off > 0; off >>= 1)
        acc += __shfl_down(acc, off, 64);
    __shared__ float smem[BLOCK / 64];
    const int lane = threadIdx.x & 63;
    const int wave = threadIdx.x >> 6;
    if (lane == 0) smem[wave] = acc;
    __syncthreads();
    float s = 0.0f;
    if (threadIdx.x == 0) {
        #pragma unroll
        for (int w = 0; w < BLOCK / 64; ++w) s += smem[w];
    }
    return s;
}

// R4 pipeline + NONTEMPORAL loads (nt flag: no L2/L3 allocation).
// Theory: harness input-restore leaves L3 full of dirty d_in lines; normal
// streaming reads allocate-on-miss and force dirty writebacks (observed 55 MB
// kernel WRITE_SIZE for a 4-byte-output kernel). nt loads skip allocation.
template <int BLOCK, int D, int CHUNKS>
__global__ void __launch_bounds__(BLOCK, 4)
focal_partial(const float* __restrict__ p, const int* __restrict__ y,
              float* __restrict__ partial, long long n) {
    constexpr int VPB = BLOCK * D * CHUNKS;  // float4s per block
    const long long n4 = n >> 2;
    const f32x4* __restrict__ p4 = (const f32x4*)p;
    const i32x4* __restrict__ y4 = (const i32x4*)y;
    const long long blk = (long long)blockIdx.x * VPB;
    const int t = threadIdx.x;

    float acc = 0.0f;
    if (blk + VPB <= n4) {
        const long long base = blk + t;
        f32x4 pv[D]; i32x4 yv[D];
        #pragma unroll
        for (int d = 0; d < D; ++d) {
            pv[d] = __builtin_nontemporal_load(&p4[base + d * BLOCK]);
            yv[d] = __builtin_nontemporal_load(&y4[base + d * BLOCK]);
        }
        #pragma unroll 1   // keep rolled: preserve the pipeline structure
        for (int c = 1; c < CHUNKS; ++c) {
            f32x4 np[D]; i32x4 ny[D];
            const long long cb = base + (long long)c * (D * BLOCK);
            #pragma unroll
            for (int d = 0; d < D; ++d) {
                np[d] = __builtin_nontemporal_load(&p4[cb + d * BLOCK]);
                ny[d] = __builtin_nontemporal_load(&y4[cb + d * BLOCK]);
            }
            #pragma unroll
            for (int d = 0; d < D; ++d) acc += focal4(pv[d], yv[d]);
            #pragma unroll
            for (int d = 0; d < D; ++d) { pv[d] = np[d]; yv[d] = ny[d]; }
        }
        #pragma unroll
        for (int d = 0; d < D; ++d) acc += focal4(pv[d], yv[d]);
    } else {
        // tail block (not hit for the bench shape)
        for (long long i = blk + t; i < n4; i += BLOCK)
            acc += focal4(p4[i], y4[i]);
    }
    // scalar remainder (n % 4), done once by the last block
    if (blockIdx.x == gridDim.x - 1 && t == 0) {
        for (long long j = n4 << 2; j < n; ++j)
            acc += focal_elem(p[j], y[j]);
    }

    const float s = block_reduce<BLOCK>(acc);
    if (t == 0) partial[blockIdx.x] = s;
}

template <int BLOCK>
__global__ void __launch_bounds__(BLOCK)
focal_final(const float* __restrict__ partial, int nparts,
            float* __restrict__ out, long long n) {
    float acc = 0.0f;
    for (int i = threadIdx.x; i < nparts; i += BLOCK) acc += partial[i];
    const float s = block_reduce<BLOCK>(acc);
    if (threadIdx.x == 0) out[0] = s / (float)n;
}

extern "C" void kernel_launch(void* const* d_in, const int* in_sizes, int n_in,
                              void* d_out, int out_size, void* d_ws, size_t ws_size,
                              hipStream_t stream) {
    const float* p = (const float*)d_in[0];
    const int*   y = (const int*)d_in[1];
    float* out = (float*)d_out;
    float* partial = (float*)d_ws;

    const long long n = (long long)in_sizes[0];
    constexpr int BLOCK = 256;
    constexpr int D = 4;       // pairs in flight per wave: 4 x (16B+16B) x 64 lanes = 8 KB
    constexpr int CHUNKS = 4;  // VPB = 4096 float4s per block
    constexpr int VPB = BLOCK * D * CHUNKS;
    const long long n4 = n >> 2;
    int nblocks = (int)((n4 + VPB - 1) / VPB);  // 1728 for n=28,311,552 (exact)
    if (nblocks < 1) nblocks = 1;

    focal_partial<BLOCK, D, CHUNKS><<<nblocks, BLOCK, 0, stream>>>(p, y, partial, n);
    focal_final<BLOCK><<<1, BLOCK, 0, stream>>>(partial, nblocks, out, n);
}

// Round 6
// 216.559 us; speedup vs baseline: 1.1237x; 1.0107x over previous
//
#include <hip/hip_runtime.h>
#include <math.h>

#define ALPHA 0.7f
#define EPSF  1e-7f

// clang ext_vector types so __builtin_nontemporal_load accepts them
typedef float f32x4 __attribute__((ext_vector_type(4)));
typedef int   i32x4 __attribute__((ext_vector_type(4)));

// focal element: pt = pos ? p : 1-p; lg = -log(pt) (inf -> 1e-7);
// f = (1-pt)^2 * lg; pos gets * ALPHA
// __logf -> v_log_f32; v_log_f32(0) = -inf so the inf->EPS path is preserved.
__device__ __forceinline__ float focal_elem(float p, int y) {
    const bool pos = (y == 1);
    const float pt = pos ? p : 1.0f - p;
    float lg = -__logf(pt);
    if (isinf(lg)) lg = EPSF;
    const float om = 1.0f - pt;
    float f = om * om * lg;
    return pos ? f * ALPHA : f;
}

__device__ __forceinline__ float focal4(const f32x4 pv, const i32x4 yv) {
    float a = focal_elem(pv.x, yv.x);
    a += focal_elem(pv.y, yv.y);
    a += focal_elem(pv.z, yv.z);
    a += focal_elem(pv.w, yv.w);
    return a;
}

template <int BLOCK>
__device__ __forceinline__ float block_reduce(float acc) {
    #pragma unroll
    for (int off = 32; off > 0; off >>= 1)
        acc += __shfl_down(acc, off, 64);
    __shared__ float smem[BLOCK / 64];
    const int lane = threadIdx.x & 63;
    const int wave = threadIdx.x >> 6;
    if (lane == 0) smem[wave] = acc;
    __syncthreads();
    float s = 0.0f;
    if (threadIdx.x == 0) {
        #pragma unroll
        for (int w = 0; w < BLOCK / 64; ++w) s += smem[w];
    }
    return s;
}

// R5 structure (explicit SW pipeline + nontemporal loads: no L2/L3 allocation,
// avoids dirty-L3 churn from the harness input-restore — the R0-R4 2.6 TB/s wall).
// R6: VPB halved 4096->2048 so the grid doubles to 3456 blocks (13.5/CU) — the
// 1728-block grid could only keep ~12.5 of 32 waves/CU resident (39% occupancy).
template <int BLOCK, int D, int CHUNKS>
__global__ void __launch_bounds__(BLOCK, 4)
focal_partial(const float* __restrict__ p, const int* __restrict__ y,
              float* __restrict__ partial, long long n) {
    constexpr int VPB = BLOCK * D * CHUNKS;  // float4s per block
    const long long n4 = n >> 2;
    const f32x4* __restrict__ p4 = (const f32x4*)p;
    const i32x4* __restrict__ y4 = (const i32x4*)y;
    const long long blk = (long long)blockIdx.x * VPB;
    const int t = threadIdx.x;

    float acc = 0.0f;
    if (blk + VPB <= n4) {
        const long long base = blk + t;
        f32x4 pv[D]; i32x4 yv[D];
        #pragma unroll
        for (int d = 0; d < D; ++d) {
            pv[d] = __builtin_nontemporal_load(&p4[base + d * BLOCK]);
            yv[d] = __builtin_nontemporal_load(&y4[base + d * BLOCK]);
        }
        #pragma unroll 1   // keep rolled: preserve the pipeline structure
        for (int c = 1; c < CHUNKS; ++c) {
            f32x4 np[D]; i32x4 ny[D];
            const long long cb = base + (long long)c * (D * BLOCK);
            #pragma unroll
            for (int d = 0; d < D; ++d) {
                np[d] = __builtin_nontemporal_load(&p4[cb + d * BLOCK]);
                ny[d] = __builtin_nontemporal_load(&y4[cb + d * BLOCK]);
            }
            #pragma unroll
            for (int d = 0; d < D; ++d) acc += focal4(pv[d], yv[d]);
            #pragma unroll
            for (int d = 0; d < D; ++d) { pv[d] = np[d]; yv[d] = ny[d]; }
        }
        #pragma unroll
        for (int d = 0; d < D; ++d) acc += focal4(pv[d], yv[d]);
    } else {
        // tail block (not hit for the bench shape)
        for (long long i = blk + t; i < n4; i += BLOCK)
            acc += focal4(p4[i], y4[i]);
    }
    // scalar remainder (n % 4), done once by the last block
    if (blockIdx.x == gridDim.x - 1 && t == 0) {
        for (long long j = n4 << 2; j < n; ++j)
            acc += focal_elem(p[j], y[j]);
    }

    const float s = block_reduce<BLOCK>(acc);
    if (t == 0) partial[blockIdx.x] = s;
}

template <int BLOCK>
__global__ void __launch_bounds__(BLOCK)
focal_final(const float* __restrict__ partial, int nparts,
            float* __restrict__ out, long long n) {
    float acc = 0.0f;
    for (int i = threadIdx.x; i < nparts; i += BLOCK) acc += partial[i];
    const float s = block_reduce<BLOCK>(acc);
    if (threadIdx.x == 0) out[0] = s / (float)n;
}

extern "C" void kernel_launch(void* const* d_in, const int* in_sizes, int n_in,
                              void* d_out, int out_size, void* d_ws, size_t ws_size,
                              hipStream_t stream) {
    const float* p = (const float*)d_in[0];
    const int*   y = (const int*)d_in[1];
    float* out = (float*)d_out;
    float* partial = (float*)d_ws;

    const long long n = (long long)in_sizes[0];
    constexpr int BLOCK = 256;
    constexpr int D = 4;       // pairs in flight per wave: 4 x (16B+16B) x 64 lanes = 8 KB
    constexpr int CHUNKS = 2;  // VPB = 2048 float4s per block -> 3456 blocks
    constexpr int VPB = BLOCK * D * CHUNKS;
    const long long n4 = n >> 2;
    int nblocks = (int)((n4 + VPB - 1) / VPB);  // 3456 for n=28,311,552 (exact)
    if (nblocks < 1) nblocks = 1;

    focal_partial<BLOCK, D, CHUNKS><<<nblocks, BLOCK, 0, stream>>>(p, y, partial, n);
    focal_final<BLOCK><<<1, BLOCK, 0, stream>>>(partial, nblocks, out, n);
}